// Round 1
// baseline (14650.571 us; speedup 1.0000x reference)
//
#include <hip/hip_runtime.h>
#include <math.h>

#define Bq 512
#define Tq 256
#define Pq 61
#define Hq 256
#define LATq 512
#define DECq 32
#define BH (Bq*Hq)   // 131072

// d_out layout (floats): notes | z | mu | log_var
#define NOTES_SZ (Bq*Tq*Pq)
#define Z_OFF  (NOTES_SZ)
#define Z_SZ   (Bq*Tq*DECq)
#define MU_OFF (Z_OFF + Z_SZ)
#define MU_SZ  (Bq*Tq*LATq)
#define LV_OFF (MU_OFF + MU_SZ)

__device__ __forceinline__ float sigmf(float x){ return 1.f/(1.f+expf(-x)); }

// ---------------------------------------------------------------- init
__global__ __launch_bounds__(256) void zero_ws(float* ws){
  int i = blockIdx.x*256 + threadIdx.x;
  if (i < 6*BH) ws[i] = 0.f;
}

// ---------------------------------------------------------------- encoder step (pipelined)
// blockIdx.z: 0 = gates fwd, 1 = gates bwd, 2 = proj fwd (step s-1), 3 = proj bwd (step s-1)
// ws: h_f[2] | c_f | h_b[2] | c_b  (each BH floats)
__global__ __launch_bounds__(256)
void enc_step(int s,
              const float* __restrict__ x,
              const float* __restrict__ Wih_f, const float* __restrict__ Whh_f, const float* __restrict__ b_f,
              const float* __restrict__ Wih_b, const float* __restrict__ Whh_b, const float* __restrict__ b_b,
              const float* __restrict__ Wout, const float* __restrict__ bout,
              float* __restrict__ ws, float* __restrict__ out)
{
  const int tid = threadIdx.x;
  const int phase = blockIdx.z;
  float* hf0 = ws;          float* hf1 = ws + BH;
  float* cf  = ws + 2*BH;
  float* hb0 = ws + 3*BH;   float* hb1 = ws + 4*BH;
  float* cb  = ws + 5*BH;

  if (phase < 2) {
    // ---------------- gates + pointwise update for step s ----------------
    if (s >= Tq) return;
    const int dir = phase;
    const int t   = dir ? (Tq-1-s) : s;
    const float* Wih  = dir ? Wih_b : Wih_f;
    const float* Whh  = dir ? Whh_b : Whh_f;
    const float* bias = dir ? b_b   : b_f;
    float* hin  = dir ? ((s&1) ? hb1 : hb0) : ((s&1) ? hf1 : hf0);
    float* hout = dir ? ((s&1) ? hb0 : hb1) : ((s&1) ? hf0 : hf1);
    float* cc   = dir ? cb : cf;

    const int k0 = blockIdx.x * 16;   // hidden-unit slice (16 wide), 16 slices
    const int m0 = blockIdx.y * 64;   // batch tile (64 rows), 8 tiles

    __shared__ float As[16][68];      // [kk][row]
    __shared__ float Bs[4][16][17];   // [gate][kk][col]

    const int tx = tid & 15;          // hidden col within slice
    const int ty = tid >> 4;          // row group (4 rows each)

    float acc[4][4];                  // [gate][row]
    #pragma unroll
    for (int g=0; g<4; ++g)
      #pragma unroll
      for (int r=0; r<4; ++r) acc[g][r] = 0.f;

    for (int kc = 0; kc < 317; kc += 16) {
      #pragma unroll
      for (int i=0;i<4;++i) {
        int idx = tid + i*256;            // 0..1023
        int kk  = idx & 15;
        int row = idx >> 4;
        int k = kc + kk;
        int m = m0 + row;
        float v;
        if (k < 61)       v = x[((long)m*Tq + t)*61 + k];
        else if (k < 317) v = hin[m*Hq + (k-61)];
        else              v = 0.f;
        As[kk][row] = v;
      }
      #pragma unroll
      for (int i=0;i<4;++i) {
        int idx = tid + i*256;
        int kk  = idx & 15;
        int col = (idx >> 4) & 15;
        int g   = idx >> 8;
        int n = g*256 + k0 + col;
        int k = kc + kk;
        float v;
        if (k < 61)       v = Wih[n*61 + k];
        else if (k < 317) v = Whh[n*256 + (k-61)];
        else              v = 0.f;
        Bs[g][kk][col] = v;
      }
      __syncthreads();
      #pragma unroll
      for (int kk=0; kk<16; ++kk) {
        float4 a = *(const float4*)&As[kk][ty<<2];
        float av[4] = {a.x, a.y, a.z, a.w};
        float bv[4] = {Bs[0][kk][tx], Bs[1][kk][tx], Bs[2][kk][tx], Bs[3][kk][tx]};
        #pragma unroll
        for (int g=0; g<4; ++g)
          #pragma unroll
          for (int r=0; r<4; ++r)
            acc[g][r] = fmaf(av[r], bv[g], acc[g][r]);
      }
      __syncthreads();
    }

    const int hu = k0 + tx;
    const float bi  = bias[       hu];
    const float bff = bias[256  + hu];
    const float bgg = bias[512  + hu];
    const float boo = bias[768  + hu];
    #pragma unroll
    for (int r=0; r<4; ++r) {
      int m = m0 + (ty<<2) + r;
      float iv = sigmf(acc[0][r] + bi);
      float fv = sigmf(acc[1][r] + bff);
      float gv = tanhf(acc[2][r] + bgg);
      float ov = sigmf(acc[3][r] + boo);
      float cold = cc[m*Hq + hu];
      float cnew = fv*cold + iv*gv;
      float hnew = ov * tanhf(cnew);
      cc[m*Hq + hu]   = cnew;
      hout[m*Hq + hu] = hnew;
    }
  } else {
    // ---------------- projection of h from step s-1 into mu/log_var ----------------
    if (s == 0) return;
    const int dir = phase - 2;
    const int t = dir ? (Tq - s) : (s - 1);
    const float* hprev = dir ? ((s&1) ? hb1 : hb0) : ((s&1) ? hf1 : hf0);
    const bool store_mode = dir ? (t >= 128) : (t <= 127);

    const int n0 = blockIdx.x * 64;   // 16 col tiles over 1024
    const int m0 = blockIdx.y * 64;   // 8 row tiles

    __shared__ float As2[16][68];     // [kk][row]
    __shared__ float Bs2[16][68];     // [kk][col]
    const int tx = tid & 15;
    const int ty = tid >> 4;
    float acc[4][4];                  // [row][col]
    #pragma unroll
    for (int r=0;r<4;++r)
      #pragma unroll
      for (int c=0;c<4;++c) acc[r][c] = 0.f;

    for (int kc=0; kc<256; kc+=16) {
      #pragma unroll
      for (int i=0;i<4;++i){
        int idx = tid + i*256;
        int kk  = idx & 15;
        int row = idx >> 4;
        As2[kk][row] = hprev[(m0+row)*Hq + kc + kk];
        Bs2[kk][row] = Wout[(long)(n0+row)*512 + dir*256 + kc + kk];
      }
      __syncthreads();
      #pragma unroll
      for (int kk=0;kk<16;++kk){
        float4 a = *(const float4*)&As2[kk][ty<<2];
        float4 b = *(const float4*)&Bs2[kk][tx<<2];
        float av[4] = {a.x,a.y,a.z,a.w};
        float bv[4] = {b.x,b.y,b.z,b.w};
        #pragma unroll
        for (int r=0;r<4;++r)
          #pragma unroll
          for (int c=0;c<4;++c)
            acc[r][c] = fmaf(av[r], bv[c], acc[r][c]);
      }
      __syncthreads();
    }
    #pragma unroll
    for (int r=0;r<4;++r){
      int m = m0 + (ty<<2) + r;
      long bt = (long)m*Tq + t;
      int n = n0 + (tx<<2);
      float* base = (n < 512) ? (out + MU_OFF + bt*512 + n)
                              : (out + LV_OFF + bt*512 + (n-512));
      float4 v = make_float4(acc[r][0], acc[r][1], acc[r][2], acc[r][3]);
      if (store_mode) {
        v.x += bout[n]; v.y += bout[n+1]; v.z += bout[n+2]; v.w += bout[n+3];
      } else {
        float4 old = *(const float4*)base;
        v.x += old.x; v.y += old.y; v.z += old.z; v.w += old.w;
      }
      *(float4*)base = v;
    }
  }
}

// ---------------------------------------------------------------- softplus/reparam + Wz
__global__ __launch_bounds__(256)
void finalize_z(const float* __restrict__ eps, const float* __restrict__ Wz,
                const float* __restrict__ bz, float* __restrict__ out)
{
  const int bt = blockIdx.x;          // b*T + t
  const int b  = bt >> 8;             // T = 256
  const int tid = threadIdx.x;
  __shared__ float zrow[512];
  #pragma unroll
  for (int i=0;i<2;++i){
    int k = tid + i*256;
    float mu  = out[MU_OFF + (long)bt*512 + k];
    float raw = out[LV_OFF + (long)bt*512 + k];
    float lv  = (raw > 20.f) ? raw : log1pf(expf(raw));
    out[LV_OFF + (long)bt*512 + k] = lv;
    float sg = expf(2.f*lv);
    zrow[k] = mu + eps[b*512 + k] * sg;
  }
  __syncthreads();
  int o = tid >> 3;   // 0..31
  int l = tid & 7;
  float p = 0.f;
  for (int j = l; j < 512; j += 8) p = fmaf(zrow[j], Wz[o*512 + j], p);
  p += __shfl_xor(p, 1, 8);
  p += __shfl_xor(p, 2, 8);
  p += __shfl_xor(p, 4, 8);
  if (l == 0) out[Z_OFF + (long)bt*32 + o] = p + bz[o];
}

// ---------------------------------------------------------------- conductor LSTM (persistent, row-parallel)
__global__ __launch_bounds__(256)
void conductor(const float* __restrict__ Wih, const float* __restrict__ Whh,
               const float* __restrict__ bias, const float* __restrict__ out,
               float* __restrict__ emb)
{
  int tid = threadIdx.x;
  int lr  = tid >> 5;                 // local row 0..7
  int j   = tid & 31;                 // hidden unit
  int row = blockIdx.x*8 + lr;        // batch index
  __shared__ float hsh[8][33];
  __shared__ float zsh[8][33];
  float hj = 0.f, cj = 0.f;
  hsh[lr][j] = 0.f;
  const float* z = out + Z_OFF;
  for (int t=0; t<16; ++t){
    zsh[lr][j] = z[((long)row*Tq + t)*32 + j];
    __syncthreads();
    float g4[4];
    #pragma unroll
    for (int g=0; g<4; ++g){
      int rw = g*32 + j;
      float acc = bias[rw];
      #pragma unroll
      for (int k=0;k<32;++k)
        acc = fmaf(Wih[rw*32+k], zsh[lr][k], fmaf(Whh[rw*32+k], hsh[lr][k], acc));
      g4[g] = acc;
    }
    cj = sigmf(g4[1])*cj + sigmf(g4[0])*tanhf(g4[2]);
    hj = sigmf(g4[3])*tanhf(cj);
    __syncthreads();
    hsh[lr][j] = hj;
    emb[((long)row*16 + t)*32 + j] = hj;
    __syncthreads();
  }
}

// ---------------------------------------------------------------- decoder LSTM + logits + softmax (persistent)
__global__ __launch_bounds__(256)
void decoder(const float* __restrict__ x,
             const float* __restrict__ dec_h0, const float* __restrict__ dec_c0,
             const float* __restrict__ Wih, const float* __restrict__ Whh,
             const float* __restrict__ bias,
             const float* __restrict__ Wlin, const float* __restrict__ blin,
             const float* __restrict__ emb, float* __restrict__ out)
{
  int tid = threadIdx.x;
  int lr  = tid >> 5;
  int j   = tid & 31;
  int gr  = blockIdx.x*8 + lr;        // 0..8191 = b*16 + bar
  int b   = gr >> 4;
  int bar = gr & 15;
  __shared__ float sWih[128*93];      // 47.6 KB: hot weight staged in LDS
  __shared__ float hsh[8][33];
  __shared__ float esh[8][33];
  __shared__ float xsh[8][64];
  for (int i = tid; i < 128*93; i += 256) sWih[i] = Wih[i];
  float hj = dec_h0[((long)bar*Bq + b)*32 + j];
  float cj = dec_c0[((long)bar*Bq + b)*32 + j];
  esh[lr][j] = emb[((long)b*16 + bar)*32 + j];
  hsh[lr][j] = hj;
  __syncthreads();
  for (int s=0; s<16; ++s){
    int tt = bar*16 + s;
    for (int kk = j; kk < 61; kk += 32)
      xsh[lr][kk] = (tt==0) ? 0.f : x[((long)b*Tq + (tt-1))*61 + kk];
    __syncthreads();
    float g4[4];
    #pragma unroll
    for (int g=0; g<4; ++g){
      int rw = g*32 + j;
      float acc = bias[rw];
      const float* wr = sWih + rw*93;
      #pragma unroll
      for (int k=0;k<32;++k) acc = fmaf(wr[k],    esh[lr][k], acc);
      #pragma unroll
      for (int k=0;k<61;++k) acc = fmaf(wr[32+k], xsh[lr][k], acc);
      #pragma unroll
      for (int k=0;k<32;++k) acc = fmaf(Whh[rw*32+k], hsh[lr][k], acc);
      g4[g] = acc;
    }
    cj = sigmf(g4[1])*cj + sigmf(g4[0])*tanhf(g4[2]);
    hj = sigmf(g4[3])*tanhf(cj);
    __syncthreads();
    hsh[lr][j] = hj;
    __syncthreads();
    // logits + softmax over 61 pitches
    float l0, l1;
    {
      float a0 = blin[j];
      const float* w0 = Wlin + j*32;
      #pragma unroll
      for (int k=0;k<32;++k) a0 = fmaf(w0[k], hsh[lr][k], a0);
      l0 = a0;
    }
    int n1 = j + 32;
    if (n1 < 61){
      float a1 = blin[n1];
      const float* w1 = Wlin + n1*32;
      #pragma unroll
      for (int k=0;k<32;++k) a1 = fmaf(w1[k], hsh[lr][k], a1);
      l1 = a1;
    } else l1 = -INFINITY;
    float mx = fmaxf(l0, l1);
    #pragma unroll
    for (int msk=16; msk; msk>>=1) mx = fmaxf(mx, __shfl_xor(mx, msk, 32));
    float e0 = expf(l0 - mx);
    float e1 = (n1<61) ? expf(l1 - mx) : 0.f;
    float sm = e0 + e1;
    #pragma unroll
    for (int msk=16; msk; msk>>=1) sm += __shfl_xor(sm, msk, 32);
    float inv = 1.f/sm;
    long obase = ((long)b*Tq + tt)*61;
    out[obase + j] = e0*inv;
    if (n1 < 61) out[obase + n1] = e1*inv;
    __syncthreads();
  }
}

// ---------------------------------------------------------------- launch
extern "C" void kernel_launch(void* const* d_in, const int* in_sizes, int n_in,
                              void* d_out, int out_size, void* d_ws, size_t ws_size,
                              hipStream_t stream)
{
  const float* x      = (const float*)d_in[0];
  const float* eps    = (const float*)d_in[1];
  const float* dec_h0 = (const float*)d_in[2];
  const float* dec_c0 = (const float*)d_in[3];
  const float* eWihf  = (const float*)d_in[4];
  const float* eWhhf  = (const float*)d_in[5];
  const float* ebf    = (const float*)d_in[6];
  const float* eWihb  = (const float*)d_in[7];
  const float* eWhhb  = (const float*)d_in[8];
  const float* ebb    = (const float*)d_in[9];
  const float* Wout   = (const float*)d_in[10];
  const float* bout   = (const float*)d_in[11];
  const float* Wz     = (const float*)d_in[12];
  const float* bz     = (const float*)d_in[13];
  const float* cWih   = (const float*)d_in[14];
  const float* cWhh   = (const float*)d_in[15];
  const float* cbias  = (const float*)d_in[16];
  const float* dWih   = (const float*)d_in[17];
  const float* dWhh   = (const float*)d_in[18];
  const float* dbias  = (const float*)d_in[19];
  const float* Wlin   = (const float*)d_in[20];
  const float* blin   = (const float*)d_in[21];
  float* out = (float*)d_out;
  float* ws  = (float*)d_ws;
  float* emb = ws + 6*BH;      // B*TB*DEC = 262144 floats

  zero_ws<<<dim3(3072), 256, 0, stream>>>(ws);
  for (int s = 0; s <= 256; ++s)
    enc_step<<<dim3(16,8,4), 256, 0, stream>>>(s, x,
        eWihf, eWhhf, ebf, eWihb, eWhhb, ebb, Wout, bout, ws, out);
  finalize_z<<<dim3(Bq*Tq), 256, 0, stream>>>(eps, Wz, bz, out);
  conductor<<<dim3(64), 256, 0, stream>>>(cWih, cWhh, cbias, out, emb);
  decoder<<<dim3(1024), 256, 0, stream>>>(x, dec_h0, dec_c0,
      dWih, dWhh, dbias, Wlin, blin, emb, out);
}

// Round 2
// 6807.475 us; speedup vs baseline: 2.1521x; 2.1521x over previous
//
#include <hip/hip_runtime.h>
#include <math.h>

#define Bq 512
#define Tq 256
#define Pq 61
#define Hq 256
#define LATq 512
#define DECq 32

// d_out layout (floats): notes | z | mu | log_var
#define NOTES_SZ (Bq*Tq*Pq)
#define Z_OFF  (NOTES_SZ)
#define Z_SZ   (Bq*Tq*DECq)
#define MU_OFF (Z_OFF + Z_SZ)
#define MU_SZ  (Bq*Tq*LATq)
#define LV_OFF (MU_OFF + MU_SZ)

typedef _Float16 half8 __attribute__((ext_vector_type(8)));
typedef float f32x4 __attribute__((ext_vector_type(4)));
typedef _Float16 halft;

// ---- ws layout (element offsets) ----
// c   : float [2][512][256]            = 262144 f32
// hHi : half  [dir2][bank2][512][256]  = 524288 half
// hLo : half  same                     = 524288 half
// BgHi: half  [dir2][kc10][nt64][lane64][8] = 655360 half
// BgLo: half  same
// BpHi: half  [dir2][kc8][nt64][lane64][8]  = 524288 half
// BpLo: half  same
// emb : float [512][16][32]            = 262144 f32
#define C_F32   262144
#define HHALF   524288
#define BGHALF  655360
#define BPHALF  524288

__device__ __forceinline__ float sigmf(float x){ return 1.f/(1.f+expf(-x)); }

// ---------------------------------------------------------------- zero c + h banks
__global__ __launch_bounds__(256) void zero_state(float* ws){
  int i = blockIdx.x*256 + threadIdx.x;
  // c (262144 f32) + hHi (262144 f32-words) + hLo (262144 f32-words) contiguous
  if (i < 786432) ws[i] = 0.f;
}

// ---------------------------------------------------------------- weight conversion to split-fp16 fragments
__global__ __launch_bounds__(256)
void convert_w(const float* __restrict__ Wihf, const float* __restrict__ Whhf,
               const float* __restrict__ Wihb, const float* __restrict__ Whhb,
               const float* __restrict__ Wout,
               halft* __restrict__ BgHi, halft* __restrict__ BgLo,
               halft* __restrict__ BpHi, halft* __restrict__ BpLo)
{
  int gid = blockIdx.x*256 + threadIdx.x;
  if (gid < 81920) {
    // gates: gid = ((dir*10+kc)*64+nt)*64+lane
    int dir  = gid / 40960;
    int rem  = gid % 40960;
    int kc   = rem / 4096;
    int nt   = (rem % 4096) / 64;
    int lane = rem % 64;
    int n = nt*16 + (lane & 15);           // interleaved col: hu*4+g
    int hu = n >> 2, g = n & 3;
    int nrow = g*256 + hu;                 // original gate row
    int kbase = kc*32 + (lane >> 4)*8;
    const float* Wih = dir ? Wihb : Wihf;
    const float* Whh = dir ? Whhb : Whhf;
    half8 hi, lo;
    #pragma unroll
    for (int j=0;j<8;++j){
      int k = kbase + j;
      float v;
      if (k < 256)            v = Whh[(long)nrow*256 + k];
      else if (k - 256 < 61)  v = Wih[(long)nrow*61 + (k - 256)];
      else                    v = 0.f;
      halft h = (halft)v;
      hi[j] = h;
      lo[j] = (halft)(v - (float)h);
    }
    *(half8*)(BgHi + (long)gid*8) = hi;
    *(half8*)(BgLo + (long)gid*8) = lo;
  } else if (gid < 81920 + 65536) {
    // proj: pid = ((dir*8+kc)*64+nt)*64+lane
    int pid  = gid - 81920;
    int dir  = pid / 32768;
    int rem  = pid % 32768;
    int kc   = rem / 4096;
    int nt   = (rem % 4096) / 64;
    int lane = rem % 64;
    int n = nt*16 + (lane & 15);           // natural col: mu|lv
    int kbase = kc*32 + (lane >> 4)*8;
    half8 hi, lo;
    #pragma unroll
    for (int j=0;j<8;++j){
      int k = kbase + j;
      float v = Wout[(long)n*512 + dir*256 + k];
      halft h = (halft)v;
      hi[j] = h;
      lo[j] = (halft)(v - (float)h);
    }
    *(half8*)(BpHi + (long)pid*8) = hi;
    *(half8*)(BpLo + (long)pid*8) = lo;
  }
}

// ---------------------------------------------------------------- encoder step: split-fp16 MFMA
// blockIdx.z: 0/1 = gates dir, 2/3 = proj dir.  grid (16, 8, 4), 256 threads.
__global__ __launch_bounds__(256)
void enc_step(int s,
              const float* __restrict__ x,
              const float* __restrict__ b_f, const float* __restrict__ b_b,
              const float* __restrict__ bout,
              float* __restrict__ cst,
              halft* __restrict__ hHi, halft* __restrict__ hLo,
              const halft* __restrict__ BgHi, const halft* __restrict__ BgLo,
              const halft* __restrict__ BpHi, const halft* __restrict__ BpLo,
              float* __restrict__ out)
{
  __shared__ float Ct[64][72];
  const int tid  = threadIdx.x;
  const int w    = tid >> 6;
  const int lane = tid & 63;
  const int quad = lane >> 4;
  const int l15  = lane & 15;
  const int phase = blockIdx.z;
  const int m = blockIdx.y*64 + w*16 + l15;     // A-fragment row

  if (phase < 2) {
    // ================= gates GEMM (K = 320 = [h 256 | x 61 pad]) + pointwise =================
    if (s >= Tq) return;
    const int dir = phase;
    const int t = dir ? (Tq-1-s) : s;
    const int bank = s & 1, obank = bank ^ 1;
    const halft* hHiB = hHi + ((long)(dir*2 + bank)*512)*256;
    const halft* hLoB = hLo + ((long)(dir*2 + bank)*512)*256;

    f32x4 acc[4];
    #pragma unroll
    for (int i=0;i<4;++i) acc[i] = (f32x4){0.f,0.f,0.f,0.f};

    for (int kc = 0; kc < 10; ++kc) {
      half8 ahi, alo;
      if (kc < 8) {
        long ao = (long)m*256 + kc*32 + quad*8;
        ahi = *(const half8*)(hHiB + ao);
        alo = *(const half8*)(hLoB + ao);
      } else {
        int k0 = (kc-8)*32 + quad*8;          // x index base, 0..56
        #pragma unroll
        for (int j=0;j<8;++j){
          int kk = k0 + j;
          float v = (kk < 61) ? x[((long)m*Tq + t)*61 + kk] : 0.f;
          halft h = (halft)v;
          ahi[j] = h;
          alo[j] = (halft)(v - (float)h);
        }
      }
      const halft* bgh = BgHi + (((long)(dir*10 + kc)*64 + blockIdx.x*4)*64 + lane)*8;
      const halft* bgl = BgLo + (((long)(dir*10 + kc)*64 + blockIdx.x*4)*64 + lane)*8;
      #pragma unroll
      for (int nt2=0; nt2<4; ++nt2) {
        half8 bhi = *(const half8*)(bgh + nt2*512);
        half8 blo = *(const half8*)(bgl + nt2*512);
        acc[nt2] = __builtin_amdgcn_mfma_f32_16x16x32_f16(ahi, bhi, acc[nt2], 0,0,0);
        acc[nt2] = __builtin_amdgcn_mfma_f32_16x16x32_f16(ahi, blo, acc[nt2], 0,0,0);
        acc[nt2] = __builtin_amdgcn_mfma_f32_16x16x32_f16(alo, bhi, acc[nt2], 0,0,0);
        acc[nt2] = __builtin_amdgcn_mfma_f32_16x16x32_f16(alo, blo, acc[nt2], 0,0,0);
      }
    }
    // stage C tile to LDS
    #pragma unroll
    for (int nt2=0; nt2<4; ++nt2)
      #pragma unroll
      for (int r=0;r<4;++r)
        Ct[w*16 + quad*4 + r][nt2*16 + l15] = acc[nt2][r];
    __syncthreads();
    // pointwise: 64 rows x 16 hidden units per block
    const float* bias = dir ? b_b : b_f;
    #pragma unroll
    for (int it=0; it<4; ++it) {
      int idx = tid + it*256;
      int r = idx & 63, u = idx >> 6;
      int mm = blockIdx.y*64 + r;
      int hu = blockIdx.x*16 + u;
      float gi = Ct[r][u*4+0] + bias[      hu];
      float gf = Ct[r][u*4+1] + bias[256 + hu];
      float gg = Ct[r][u*4+2] + bias[512 + hu];
      float go = Ct[r][u*4+3] + bias[768 + hu];
      float* cp = cst + ((long)dir*512 + mm)*256 + hu;
      float cold = *cp;
      float cnew = sigmf(gf)*cold + sigmf(gi)*tanhf(gg);
      float hnew = sigmf(go)*tanhf(cnew);
      *cp = cnew;
      long ho = ((long)(dir*2 + obank)*512 + mm)*256 + hu;
      halft hh = (halft)hnew;
      hHi[ho] = hh;
      hLo[ho] = (halft)(hnew - (float)hh);
    }
  } else {
    // ================= proj GEMM: h(s-1) @ Wout^T slice (K=256) =================
    if (s == 0) return;
    const int dir = phase - 2;
    const int t = dir ? (Tq - s) : (s - 1);
    const int bank = s & 1;
    const bool store_mode = dir ? (t >= 128) : (t <= 127);
    const halft* hHiB = hHi + ((long)(dir*2 + bank)*512)*256;
    const halft* hLoB = hLo + ((long)(dir*2 + bank)*512)*256;

    f32x4 acc[4];
    #pragma unroll
    for (int i=0;i<4;++i) acc[i] = (f32x4){0.f,0.f,0.f,0.f};

    for (int kc = 0; kc < 8; ++kc) {
      long ao = (long)m*256 + kc*32 + quad*8;
      half8 ahi = *(const half8*)(hHiB + ao);
      half8 alo = *(const half8*)(hLoB + ao);
      const halft* bph = BpHi + (((long)(dir*8 + kc)*64 + blockIdx.x*4)*64 + lane)*8;
      const halft* bpl = BpLo + (((long)(dir*8 + kc)*64 + blockIdx.x*4)*64 + lane)*8;
      #pragma unroll
      for (int nt2=0; nt2<4; ++nt2) {
        half8 bhi = *(const half8*)(bph + nt2*512);
        half8 blo = *(const half8*)(bpl + nt2*512);
        acc[nt2] = __builtin_amdgcn_mfma_f32_16x16x32_f16(ahi, bhi, acc[nt2], 0,0,0);
        acc[nt2] = __builtin_amdgcn_mfma_f32_16x16x32_f16(ahi, blo, acc[nt2], 0,0,0);
        acc[nt2] = __builtin_amdgcn_mfma_f32_16x16x32_f16(alo, bhi, acc[nt2], 0,0,0);
        acc[nt2] = __builtin_amdgcn_mfma_f32_16x16x32_f16(alo, blo, acc[nt2], 0,0,0);
      }
    }
    #pragma unroll
    for (int nt2=0; nt2<4; ++nt2)
      #pragma unroll
      for (int r=0;r<4;++r)
        Ct[w*16 + quad*4 + r][nt2*16 + l15] = acc[nt2][r];
    __syncthreads();
    // epilogue: RMW into mu / log_var
    #pragma unroll
    for (int it=0; it<4; ++it) {
      int idx = tid + it*256;
      int r = idx & 63, c4 = idx >> 6;
      int n = blockIdx.x*64 + c4*4;
      long bt = (long)(blockIdx.y*64 + r)*Tq + t;
      float* dst = (n < 512) ? (out + MU_OFF + bt*512 + n)
                             : (out + LV_OFF + bt*512 + (n-512));
      float4 v = *(const float4*)&Ct[r][c4*4];
      if (store_mode) {
        v.x += bout[n]; v.y += bout[n+1]; v.z += bout[n+2]; v.w += bout[n+3];
      } else {
        float4 old = *(const float4*)dst;
        v.x += old.x; v.y += old.y; v.z += old.z; v.w += old.w;
      }
      *(float4*)dst = v;
    }
  }
}

// ---------------------------------------------------------------- softplus/reparam + Wz
__global__ __launch_bounds__(256)
void finalize_z(const float* __restrict__ eps, const float* __restrict__ Wz,
                const float* __restrict__ bz, float* __restrict__ out)
{
  const int bt = blockIdx.x;
  const int b  = bt >> 8;
  const int tid = threadIdx.x;
  __shared__ float zrow[512];
  #pragma unroll
  for (int i=0;i<2;++i){
    int k = tid + i*256;
    float mu  = out[MU_OFF + (long)bt*512 + k];
    float raw = out[LV_OFF + (long)bt*512 + k];
    float lv  = (raw > 20.f) ? raw : log1pf(expf(raw));
    out[LV_OFF + (long)bt*512 + k] = lv;
    float sg = expf(2.f*lv);
    zrow[k] = mu + eps[b*512 + k] * sg;
  }
  __syncthreads();
  int o = tid >> 3;
  int l = tid & 7;
  float p = 0.f;
  for (int j = l; j < 512; j += 8) p = fmaf(zrow[j], Wz[o*512 + j], p);
  p += __shfl_xor(p, 1, 8);
  p += __shfl_xor(p, 2, 8);
  p += __shfl_xor(p, 4, 8);
  if (l == 0) out[Z_OFF + (long)bt*32 + o] = p + bz[o];
}

// ---------------------------------------------------------------- conductor LSTM
__global__ __launch_bounds__(256)
void conductor(const float* __restrict__ Wih, const float* __restrict__ Whh,
               const float* __restrict__ bias, const float* __restrict__ out,
               float* __restrict__ emb)
{
  int tid = threadIdx.x;
  int lr  = tid >> 5;
  int j   = tid & 31;
  int row = blockIdx.x*8 + lr;
  __shared__ float hsh[8][33];
  __shared__ float zsh[8][33];
  float hj = 0.f, cj = 0.f;
  hsh[lr][j] = 0.f;
  const float* z = out + Z_OFF;
  for (int t=0; t<16; ++t){
    zsh[lr][j] = z[((long)row*Tq + t)*32 + j];
    __syncthreads();
    float g4[4];
    #pragma unroll
    for (int g=0; g<4; ++g){
      int rw = g*32 + j;
      float acc = bias[rw];
      #pragma unroll
      for (int k=0;k<32;++k)
        acc = fmaf(Wih[rw*32+k], zsh[lr][k], fmaf(Whh[rw*32+k], hsh[lr][k], acc));
      g4[g] = acc;
    }
    cj = sigmf(g4[1])*cj + sigmf(g4[0])*tanhf(g4[2]);
    hj = sigmf(g4[3])*tanhf(cj);
    __syncthreads();
    hsh[lr][j] = hj;
    emb[((long)row*16 + t)*32 + j] = hj;
    __syncthreads();
  }
}

// ---------------------------------------------------------------- decoder LSTM + logits + softmax
__global__ __launch_bounds__(256)
void decoder(const float* __restrict__ x,
             const float* __restrict__ dec_h0, const float* __restrict__ dec_c0,
             const float* __restrict__ Wih, const float* __restrict__ Whh,
             const float* __restrict__ bias,
             const float* __restrict__ Wlin, const float* __restrict__ blin,
             const float* __restrict__ emb, float* __restrict__ out)
{
  int tid = threadIdx.x;
  int lr  = tid >> 5;
  int j   = tid & 31;
  int gr  = blockIdx.x*8 + lr;
  int b   = gr >> 4;
  int bar = gr & 15;
  __shared__ float sWih[128*93];
  __shared__ float hsh[8][33];
  __shared__ float esh[8][33];
  __shared__ float xsh[8][64];
  for (int i = tid; i < 128*93; i += 256) sWih[i] = Wih[i];
  float hj = dec_h0[((long)bar*Bq + b)*32 + j];
  float cj = dec_c0[((long)bar*Bq + b)*32 + j];
  esh[lr][j] = emb[((long)b*16 + bar)*32 + j];
  hsh[lr][j] = hj;
  __syncthreads();
  for (int s=0; s<16; ++s){
    int tt = bar*16 + s;
    for (int kk = j; kk < 61; kk += 32)
      xsh[lr][kk] = (tt==0) ? 0.f : x[((long)b*Tq + (tt-1))*61 + kk];
    __syncthreads();
    float g4[4];
    #pragma unroll
    for (int g=0; g<4; ++g){
      int rw = g*32 + j;
      float acc = bias[rw];
      const float* wr = sWih + rw*93;
      #pragma unroll
      for (int k=0;k<32;++k) acc = fmaf(wr[k],    esh[lr][k], acc);
      #pragma unroll
      for (int k=0;k<61;++k) acc = fmaf(wr[32+k], xsh[lr][k], acc);
      #pragma unroll
      for (int k=0;k<32;++k) acc = fmaf(Whh[rw*32+k], hsh[lr][k], acc);
      g4[g] = acc;
    }
    cj = sigmf(g4[1])*cj + sigmf(g4[0])*tanhf(g4[2]);
    hj = sigmf(g4[3])*tanhf(cj);
    __syncthreads();
    hsh[lr][j] = hj;
    __syncthreads();
    float l0, l1;
    {
      float a0 = blin[j];
      const float* w0 = Wlin + j*32;
      #pragma unroll
      for (int k=0;k<32;++k) a0 = fmaf(w0[k], hsh[lr][k], a0);
      l0 = a0;
    }
    int n1 = j + 32;
    if (n1 < 61){
      float a1 = blin[n1];
      const float* w1 = Wlin + n1*32;
      #pragma unroll
      for (int k=0;k<32;++k) a1 = fmaf(w1[k], hsh[lr][k], a1);
      l1 = a1;
    } else l1 = -INFINITY;
    float mx = fmaxf(l0, l1);
    #pragma unroll
    for (int msk=16; msk; msk>>=1) mx = fmaxf(mx, __shfl_xor(mx, msk, 32));
    float e0 = expf(l0 - mx);
    float e1 = (n1<61) ? expf(l1 - mx) : 0.f;
    float sm = e0 + e1;
    #pragma unroll
    for (int msk=16; msk; msk>>=1) sm += __shfl_xor(sm, msk, 32);
    float inv = 1.f/sm;
    long obase = ((long)b*Tq + tt)*61;
    out[obase + j] = e0*inv;
    if (n1 < 61) out[obase + n1] = e1*inv;
    __syncthreads();
  }
}

// ---------------------------------------------------------------- launch
extern "C" void kernel_launch(void* const* d_in, const int* in_sizes, int n_in,
                              void* d_out, int out_size, void* d_ws, size_t ws_size,
                              hipStream_t stream)
{
  const float* x      = (const float*)d_in[0];
  const float* eps    = (const float*)d_in[1];
  const float* dec_h0 = (const float*)d_in[2];
  const float* dec_c0 = (const float*)d_in[3];
  const float* eWihf  = (const float*)d_in[4];
  const float* eWhhf  = (const float*)d_in[5];
  const float* ebf    = (const float*)d_in[6];
  const float* eWihb  = (const float*)d_in[7];
  const float* eWhhb  = (const float*)d_in[8];
  const float* ebb    = (const float*)d_in[9];
  const float* Wout   = (const float*)d_in[10];
  const float* bout   = (const float*)d_in[11];
  const float* Wz     = (const float*)d_in[12];
  const float* bz     = (const float*)d_in[13];
  const float* cWih   = (const float*)d_in[14];
  const float* cWhh   = (const float*)d_in[15];
  const float* cbias  = (const float*)d_in[16];
  const float* dWih   = (const float*)d_in[17];
  const float* dWhh   = (const float*)d_in[18];
  const float* dbias  = (const float*)d_in[19];
  const float* Wlin   = (const float*)d_in[20];
  const float* blin   = (const float*)d_in[21];
  float* out = (float*)d_out;

  float* ws   = (float*)d_ws;
  float* cst  = ws;                                  // 262144 f32
  halft* hHi  = (halft*)(ws + C_F32);                // 524288 half
  halft* hLo  = hHi + HHALF;                         // 524288 half
  halft* BgHi = hLo + HHALF;                         // 655360 half
  halft* BgLo = BgHi + BGHALF;
  halft* BpHi = BgLo + BGHALF;                       // 524288 half
  halft* BpLo = BpHi + BPHALF;
  float* emb  = (float*)(BpLo + BPHALF);             // 262144 f32

  zero_state<<<dim3(3072), 256, 0, stream>>>(ws);
  convert_w<<<dim3(576), 256, 0, stream>>>(eWihf, eWhhf, eWihb, eWhhb, Wout,
                                           BgHi, BgLo, BpHi, BpLo);
  for (int s = 0; s <= 256; ++s)
    enc_step<<<dim3(16,8,4), 256, 0, stream>>>(s, x, ebf, ebb, bout,
        cst, hHi, hLo, BgHi, BgLo, BpHi, BpLo, out);
  finalize_z<<<dim3(Bq*Tq), 256, 0, stream>>>(eps, Wz, bz, out);
  conductor<<<dim3(64), 256, 0, stream>>>(cWih, cWhh, cbias, out + 0, emb);
  decoder<<<dim3(1024), 256, 0, stream>>>(x, dec_h0, dec_c0,
      dWih, dWhh, dbias, Wlin, blin, emb, out);
}